// Round 1
// baseline (1810.090 us; speedup 1.0000x reference)
//
#include <hip/hip_runtime.h>

#define B_   8
#define C_   256
#define D_   32
#define N_   4096
#define BI   32
#define BJ   32

// ---------------------------------------------------------------------------
// Kernel 1: 1x1-conv projections.
//   qT[b][i][d]  = sum_c q_w[d][c]*x[b][c][i] + q_b[d]     (d=0..31)
//   vws[b][i][c] = sum_k v_w[c][k]*x[b][k][i] + v_b[c]     (c=0..255)
// One block = one (b, 64-pixel tile). x tile staged in LDS [256][64].
// Wave w computes q rows w*8..w*8+7 and v rows w*64..w*64+63; weight reads
// are wave-uniform -> scalar loads.
// ---------------------------------------------------------------------------
__global__ __launch_bounds__(256) void proj_kernel(
    const float* __restrict__ x, const float* __restrict__ qw,
    const float* __restrict__ qb, const float* __restrict__ vw,
    const float* __restrict__ vb, float* __restrict__ qT,
    float* __restrict__ vws)
{
    __shared__ float xls[256 * 64];
    const int b  = blockIdx.x >> 6;
    const int i0 = (blockIdx.x & 63) * 64;
    const int t  = threadIdx.x;

    const float* xb = x + (size_t)b * C_ * N_;
    #pragma unroll
    for (int k = 0; k < 16; ++k) {
        int f4  = k * 256 + t;          // 4096 float4s = 256 rows x 16
        int c   = f4 >> 4;
        int col = (f4 & 15) << 2;
        float4 v = *(const float4*)(xb + (size_t)c * N_ + i0 + col);
        *(float4*)(xls + c * 64 + col) = v;
    }
    __syncthreads();

    const int lane = t & 63;
    const int w    = __builtin_amdgcn_readfirstlane(t >> 6);

    float accq[8], accv[64];
    #pragma unroll
    for (int k = 0; k < 8; ++k)  accq[k] = qb[w * 8 + k];
    #pragma unroll
    for (int m = 0; m < 64; ++m) accv[m] = vb[w * 64 + m];

    const float* qwp = qw + w * 8 * 256;
    const float* vwp = vw + w * 64 * 256;

    for (int c = 0; c < 256; ++c) {
        float xv = xls[c * 64 + lane];
        #pragma unroll
        for (int k = 0; k < 8; ++k)  accq[k] += qwp[k * 256 + c] * xv;
        #pragma unroll
        for (int m = 0; m < 64; ++m) accv[m] += vwp[m * 256 + c] * xv;
    }

    const int i = i0 + lane;
    float* qo = qT + ((size_t)b * N_ + i) * D_ + w * 8;
    #pragma unroll
    for (int k = 0; k < 8; ++k) qo[k] = accq[k];
    float* vo = vws + ((size_t)b * N_ + i) * C_ + w * 64;
    #pragma unroll
    for (int m = 0; m < 64; ++m) vo[m] = accv[m];
}

// ---------------------------------------------------------------------------
// Kernel 2: flash-style attention + epilogue (gamma*O/l + x).
// Block = (b, 32 query rows). 256 threads. Lane l owns channels 4l..4l+3;
// wave w owns query rows w*8..w*8+7 -> acc[8][4] in registers.
// Online softmax state per row in LDS (rowm/rowl/rowa).
// ---------------------------------------------------------------------------
__global__ __launch_bounds__(256) void attn_kernel(
    const float* __restrict__ qT, const float* __restrict__ vws,
    const float* __restrict__ x, const float* __restrict__ gamma_p,
    float* __restrict__ out)
{
    __shared__ float Qs[32][36];      // +4 pad: 16B-aligned rows, broken stride
    __shared__ float Ks[32][36];
    __shared__ float Sp[32][36];
    __shared__ float Vs[32 * 256];    // V tile [j][c], also reused for O^T
    __shared__ float rowm[32], rowl[32], rowa[32];

    const int b     = blockIdx.x >> 7;        // 128 i-tiles per batch
    const int i0    = (blockIdx.x & 127) * BI;
    const int t     = threadIdx.x;
    const int lane  = t & 63;
    const int w     = t >> 6;
    const int c0    = lane << 2;              // channel base for this lane

    // Q tile: 32 rows x 32 d = 256 float4s, one per thread
    {
        int row = t >> 3, col = (t & 7) << 2;
        float4 v = *(const float4*)(qT + ((size_t)b * N_ + i0 + row) * D_ + col);
        *(float4*)(&Qs[row][col]) = v;
    }
    if (t < 32) { rowm[t] = -1e30f; rowl[t] = 0.0f; }

    float acc[8][4];
    #pragma unroll
    for (int rr = 0; rr < 8; ++rr)
        #pragma unroll
        for (int cc = 0; cc < 4; ++cc) acc[rr][cc] = 0.0f;

    const float* vb_ = vws + (size_t)b * N_ * C_;

    for (int jt = 0; jt < N_ / BJ; ++jt) {
        const int j0 = jt * BJ;
        // stage K tile
        {
            int row = t >> 3, col = (t & 7) << 2;
            float4 v = *(const float4*)(qT + ((size_t)b * N_ + j0 + row) * D_ + col);
            *(float4*)(&Ks[row][col]) = v;
        }
        // stage V tile: 32x256 floats = 2048 float4s, 8 per thread
        #pragma unroll
        for (int k = 0; k < 8; ++k) {
            int f4 = k * 256 + t;
            float4 v = *(const float4*)(vb_ + (size_t)j0 * C_ + f4 * 4);
            *(float4*)(&Vs[f4 * 4]) = v;
        }
        __syncthreads();

        // S[i][j] = Q_i . K_j : thread -> i = t&31, j = 4*(t>>5)..+3
        {
            int i = t & 31, jj = (t >> 5) << 2;
            float4 qr[8];
            #pragma unroll
            for (int d4 = 0; d4 < 8; ++d4) qr[d4] = *(float4*)(&Qs[i][d4 * 4]);
            #pragma unroll
            for (int k = 0; k < 4; ++k) {
                float s = 0.0f;
                #pragma unroll
                for (int d4 = 0; d4 < 8; ++d4) {
                    float4 kr = *(float4*)(&Ks[jj + k][d4 * 4]);
                    s += qr[d4].x * kr.x + qr[d4].y * kr.y +
                         qr[d4].z * kr.z + qr[d4].w * kr.w;
                }
                Sp[i][jj + k] = s;
            }
        }
        __syncthreads();

        // online-softmax stats: thread r<32 owns row r; Sp row -> probabilities
        if (t < 32) {
            const int r = t;
            float mo = rowm[r], mx = mo;
            float sv[32];
            #pragma unroll
            for (int j = 0; j < 32; ++j) { sv[j] = Sp[r][j]; mx = fmaxf(mx, sv[j]); }
            float a = __expf(mo - mx), sum = 0.0f;
            #pragma unroll
            for (int j = 0; j < 32; ++j) {
                float p = __expf(sv[j] - mx);
                Sp[r][j] = p; sum += p;
            }
            rowl[r] = rowl[r] * a + sum;
            rowm[r] = mx;
            rowa[r] = a;
        }
        __syncthreads();

        // O = O*alpha + P @ V
        {
            #pragma unroll
            for (int rr = 0; rr < 8; ++rr) {
                float a = rowa[w * 8 + rr];
                #pragma unroll
                for (int cc = 0; cc < 4; ++cc) acc[rr][cc] *= a;
            }
            #pragma unroll
            for (int jg = 0; jg < 8; ++jg) {
                const int j = jg * 4;
                float4 p4[8];
                #pragma unroll
                for (int rr = 0; rr < 8; ++rr)
                    p4[rr] = *(float4*)(&Sp[w * 8 + rr][j]);  // wave-uniform bcast
                #pragma unroll
                for (int k = 0; k < 4; ++k) {
                    float4 v4 = *(const float4*)(&Vs[(j + k) * C_ + c0]);
                    #pragma unroll
                    for (int rr = 0; rr < 8; ++rr) {
                        float p = (k == 0) ? p4[rr].x : (k == 1) ? p4[rr].y
                                : (k == 2) ? p4[rr].z : p4[rr].w;
                        acc[rr][0] += p * v4.x; acc[rr][1] += p * v4.y;
                        acc[rr][2] += p * v4.z; acc[rr][3] += p * v4.w;
                    }
                }
            }
        }
        __syncthreads();   // protect Vs/Ks/Sp before next stage
    }

    // epilogue: O^T into Vs as [c][i], then coalesced store of gamma*O/l + x
    const float g = gamma_p[0];
    #pragma unroll
    for (int rr = 0; rr < 8; ++rr) {
        const int r = w * 8 + rr;
        const float s = g / rowl[r];
        #pragma unroll
        for (int cc = 0; cc < 4; ++cc)
            Vs[(c0 + cc) * 32 + r] = acc[rr][cc] * s;
    }
    __syncthreads();
    {
        const int c = t;   // one channel per thread, 32 consecutive i's
        const float* xp = x   + ((size_t)b * C_ + c) * N_ + i0;
        float*       op = out + ((size_t)b * C_ + c) * N_ + i0;
        #pragma unroll
        for (int k = 0; k < 8; ++k) {
            float4 o  = *(float4*)(&Vs[c * 32 + k * 4]);
            float4 xv = *(const float4*)(xp + k * 4);
            o.x += xv.x; o.y += xv.y; o.z += xv.z; o.w += xv.w;
            *(float4*)(op + k * 4) = o;
        }
    }
}

extern "C" void kernel_launch(void* const* d_in, const int* in_sizes, int n_in,
                              void* d_out, int out_size, void* d_ws, size_t ws_size,
                              hipStream_t stream)
{
    const float* x     = (const float*)d_in[0];
    const float* q_w   = (const float*)d_in[1];
    const float* q_b   = (const float*)d_in[2];
    const float* v_w   = (const float*)d_in[3];
    const float* v_b   = (const float*)d_in[4];
    const float* gamma = (const float*)d_in[5];
    float* out = (float*)d_out;

    float* qT  = (float*)d_ws;                       //  8*4096*32  = 1M floats
    float* vws = qT + (size_t)B_ * N_ * D_;          //  8*4096*256 = 8M floats

    proj_kernel<<<B_ * (N_ / 64), 256, 0, stream>>>(x, q_w, q_b, v_w, v_b, qT, vws);
    attn_kernel<<<B_ * (N_ / BI), 256, 0, stream>>>(qT, vws, x, gamma, out);
}

// Round 2
// 451.757 us; speedup vs baseline: 4.0068x; 4.0068x over previous
//
#include <hip/hip_runtime.h>

#define B_   8
#define C_   256
#define D_   32
#define N_   4096
#define FMX  64.0f

typedef __attribute__((ext_vector_type(8))) short bf8_t;   // 8 bf16 (4 VGPRs)
typedef __attribute__((ext_vector_type(4))) float f4_t;    // MFMA C/D frag

__device__ __forceinline__ unsigned short f2bf(float f) {   // fp32 -> bf16 RNE
    unsigned int u = __builtin_bit_cast(unsigned int, f);
    u += 0x7FFFu + ((u >> 16) & 1u);
    return (unsigned short)(u >> 16);
}
__device__ __forceinline__ float bf2f(unsigned short h) {
    unsigned int u = ((unsigned int)h) << 16;
    return __builtin_bit_cast(float, u);
}

// ---------------------------------------------------------------------------
// Kernel 1: projections -> bf16 workspace.
//   qh/ql[b][i][d] : hi/lo bf16 split of q (for fp32-accurate S via 3 MFMAs)
//   vT[b][c][i]    : bf16 V, channel-major (j-contiguous for B-fragments)
// ---------------------------------------------------------------------------
__global__ __launch_bounds__(256) void proj_kernel(
    const float* __restrict__ x, const float* __restrict__ qw,
    const float* __restrict__ qb, const float* __restrict__ vw,
    const float* __restrict__ vb, unsigned short* __restrict__ qh,
    unsigned short* __restrict__ ql, unsigned short* __restrict__ vT)
{
    __shared__ float xls[256 * 64];
    const int b  = blockIdx.x >> 6;
    const int i0 = (blockIdx.x & 63) * 64;
    const int t  = threadIdx.x;

    const float* xb = x + (size_t)b * C_ * N_;
    #pragma unroll
    for (int k = 0; k < 16; ++k) {
        int f4  = k * 256 + t;
        int c   = f4 >> 4;
        int col = (f4 & 15) << 2;
        float4 v = *(const float4*)(xb + (size_t)c * N_ + i0 + col);
        *(float4*)(xls + c * 64 + col) = v;
    }
    __syncthreads();

    const int lane = t & 63;
    const int w    = __builtin_amdgcn_readfirstlane(t >> 6);

    float accq[8], accv[64];
    #pragma unroll
    for (int k = 0; k < 8; ++k)  accq[k] = qb[w * 8 + k];
    #pragma unroll
    for (int m = 0; m < 64; ++m) accv[m] = vb[w * 64 + m];

    const float* qwp = qw + w * 8 * 256;
    const float* vwp = vw + w * 64 * 256;

    for (int c = 0; c < 256; ++c) {
        float xv = xls[c * 64 + lane];
        #pragma unroll
        for (int k = 0; k < 8; ++k)  accq[k] += qwp[k * 256 + c] * xv;
        #pragma unroll
        for (int m = 0; m < 64; ++m) accv[m] += vwp[m * 256 + c] * xv;
    }

    const int i = i0 + lane;
    // q hi/lo: 8 bf16 each = one 16B store apiece
    unsigned short hs[8], ls[8];
    #pragma unroll
    for (int k = 0; k < 8; ++k) {
        float qv = accq[k];
        hs[k] = f2bf(qv);
        ls[k] = f2bf(qv - bf2f(hs[k]));
    }
    uint4 uh, ul;
    uh.x = hs[0] | ((unsigned)hs[1] << 16); uh.y = hs[2] | ((unsigned)hs[3] << 16);
    uh.z = hs[4] | ((unsigned)hs[5] << 16); uh.w = hs[6] | ((unsigned)hs[7] << 16);
    ul.x = ls[0] | ((unsigned)ls[1] << 16); ul.y = ls[2] | ((unsigned)ls[3] << 16);
    ul.z = ls[4] | ((unsigned)ls[5] << 16); ul.w = ls[6] | ((unsigned)ls[7] << 16);
    *(uint4*)(qh + ((size_t)b * N_ + i) * D_ + w * 8) = uh;
    *(uint4*)(ql + ((size_t)b * N_ + i) * D_ + w * 8) = ul;

    // vT[b][c][i]: lane-consecutive i -> coalesced 128B per store
    #pragma unroll
    for (int m = 0; m < 64; ++m)
        vT[((size_t)b * C_ + w * 64 + m) * N_ + i] = f2bf(accv[m]);
}

// ---------------------------------------------------------------------------
// Kernel 2: MFMA flash attention, fixed softmax max (no rescale), fused epilogue.
// Block = (b, 64 query rows), 256 threads. Wave w: S columns [w*16,w*16+16),
// P.V channels [w*64,(w+1)*64). Row sums via ones-column MFMA on wave 3.
// ---------------------------------------------------------------------------
__global__ __launch_bounds__(256, 2) void attn_kernel(
    const unsigned short* __restrict__ qh, const unsigned short* __restrict__ ql,
    const unsigned short* __restrict__ vT, const float* __restrict__ x,
    const float* __restrict__ gamma_p, float* __restrict__ out)
{
    // Vs: [part(8)][c(256)+pad][j_lo(8)] bf16 — conflict-free B-frag reads
    __shared__ __align__(16) unsigned short Vs[8 * 257 * 8];   // 32896 B
    // Pb: [part(8)][i(64)][j_lo(8)] bf16 — conflict-free A-frag reads
    __shared__ __align__(16) unsigned short Pb[8 * 64 * 8];    //  8192 B
    __shared__ __align__(16) float rowl[64];

    float* T = (float*)Vs;  // epilogue transpose buffer [256][17] fp32 (aliases Vs)

    const int t    = threadIdx.x;
    const int lane = t & 63;
    const int w    = t >> 6;
    const int q4   = lane >> 4;
    const int l15  = lane & 15;
    const int b    = blockIdx.x >> 6;
    const int i0   = (blockIdx.x & 63) * 64;

    const unsigned short* qhb = qh + (size_t)b * N_ * D_;
    const unsigned short* qlb = ql + (size_t)b * N_ * D_;
    const unsigned short* vTb = vT + (size_t)b * C_ * N_;

    // Q A-fragments (resident all kernel): A[m=l15][k=q4*8+e]
    bf8_t Ah[4], Al[4];
    #pragma unroll
    for (int mt = 0; mt < 4; ++mt) {
        size_t off = (size_t)(i0 + mt * 16 + l15) * D_ + q4 * 8;
        Ah[mt] = *(const bf8_t*)(qhb + off);
        Al[mt] = *(const bf8_t*)(qlb + off);
    }

    f4_t acc[4][4];   // [mt][nt]
    #pragma unroll
    for (int mt = 0; mt < 4; ++mt)
        #pragma unroll
        for (int nt = 0; nt < 4; ++nt) acc[mt][nt] = (f4_t)0.0f;

    f4_t lacc[4];     // row-sum accumulator (wave 3's ones-column)
    #pragma unroll
    for (int mt = 0; mt < 4; ++mt) lacc[mt] = (f4_t)0.0f;
    bf8_t onesb;
    #pragma unroll
    for (int e = 0; e < 8; ++e) onesb[e] = (short)0x3F80;   // bf16 1.0

    for (int jt = 0; jt < N_ / 64; ++jt) {
        const int j0 = jt * 64;

        // K B-frags straight from global (L2-resident): B[k=d][n=j]=q_j[d]
        size_t koff = (size_t)(j0 + w * 16 + l15) * D_ + q4 * 8;
        bf8_t Bh = *(const bf8_t*)(qhb + koff);
        bf8_t Bl = *(const bf8_t*)(qlb + koff);

        __syncthreads();   // prev iter's P.V reads of Vs/Pb complete

        // stage V tile: 2048 x 16B, 8 per thread, coalesced global reads
        #pragma unroll
        for (int r = 0; r < 8; ++r) {
            int idx = r * 256 + t;
            int c = idx >> 3, part = idx & 7;
            uint4 d = *(const uint4*)(vTb + (size_t)c * N_ + j0 + part * 8);
            *(uint4*)(&Vs[(part * 257 + c) * 8]) = d;
        }

        // S = Qh.Kh + Qh.Kl + Ql.Kh  (fp32-accurate), overlaps staging loads
        f4_t s[4];
        #pragma unroll
        for (int mt = 0; mt < 4; ++mt) {
            f4_t a = (f4_t)0.0f;
            a = __builtin_amdgcn_mfma_f32_16x16x32_bf16(Ah[mt], Bh, a, 0, 0, 0);
            a = __builtin_amdgcn_mfma_f32_16x16x32_bf16(Ah[mt], Bl, a, 0, 0, 0);
            a = __builtin_amdgcn_mfma_f32_16x16x32_bf16(Al[mt], Bh, a, 0, 0, 0);
            s[mt] = a;
        }

        // P = exp(s - 64) -> bf16 into Pb (C-layout: row=q4*4+r, col=l15)
        const int jl = w * 16 + l15;
        const int pprt = jl >> 3, jlo = jl & 7;
        #pragma unroll
        for (int mt = 0; mt < 4; ++mt)
            #pragma unroll
            for (int r = 0; r < 4; ++r) {
                float p = __expf(s[mt][r] - FMX);
                Pb[(pprt * 64 + mt * 16 + q4 * 4 + r) * 8 + jlo] = f2bf(p);
            }

        __syncthreads();   // Vs + Pb ready

        // O += P.V ; wave 3 also accumulates row sums via ones-column
        #pragma unroll
        for (int kk = 0; kk < 2; ++kk) {
            bf8_t Af[4], Bf[4];
            #pragma unroll
            for (int mt = 0; mt < 4; ++mt)
                Af[mt] = *(const bf8_t*)(&Pb[((kk * 4 + q4) * 64 + mt * 16 + l15) * 8]);
            #pragma unroll
            for (int nt = 0; nt < 4; ++nt)
                Bf[nt] = *(const bf8_t*)(&Vs[((kk * 4 + q4) * 257 + w * 64 + nt * 16 + l15) * 8]);
            #pragma unroll
            for (int mt = 0; mt < 4; ++mt)
                #pragma unroll
                for (int nt = 0; nt < 4; ++nt)
                    acc[mt][nt] = __builtin_amdgcn_mfma_f32_16x16x32_bf16(
                        Af[mt], Bf[nt], acc[mt][nt], 0, 0, 0);
            if (w == 3) {
                #pragma unroll
                for (int mt = 0; mt < 4; ++mt)
                    lacc[mt] = __builtin_amdgcn_mfma_f32_16x16x32_bf16(
                        Af[mt], onesb, lacc[mt], 0, 0, 0);
            }
        }
    }

    __syncthreads();              // all P.V done; Vs free for reuse as T
    if (w == 3 && l15 == 0) {     // ones-column col 0 holds row sums
        #pragma unroll
        for (int mt = 0; mt < 4; ++mt)
            #pragma unroll
            for (int r = 0; r < 4; ++r)
                rowl[mt * 16 + q4 * 4 + r] = lacc[mt][r];
    }
    __syncthreads();

    const float g = gamma_p[0];
    for (int mt = 0; mt < 4; ++mt) {
        float4 rl = *(float4*)(&rowl[mt * 16 + q4 * 4]);
        float inv[4] = { g / rl.x, g / rl.y, g / rl.z, g / rl.w };
        // transpose O chunk into T[c][i16] (stride 17 breaks bank conflicts)
        #pragma unroll
        for (int nt = 0; nt < 4; ++nt)
            #pragma unroll
            for (int r = 0; r < 4; ++r)
                T[(w * 64 + nt * 16 + l15) * 17 + q4 * 4 + r] = acc[mt][nt][r] * inv[r];
        __syncthreads();
        // store: 4 lanes per channel -> 64B contiguous segments, fused +x
        #pragma unroll
        for (int pass = 0; pass < 4; ++pass) {
            int c  = pass * 64 + (t >> 2);
            int ii = (t & 3) * 4;
            float4 o;
            o.x = T[c * 17 + ii];     o.y = T[c * 17 + ii + 1];
            o.z = T[c * 17 + ii + 2]; o.w = T[c * 17 + ii + 3];
            size_t goff = ((size_t)b * C_ + c) * N_ + i0 + mt * 16 + ii;
            float4 xv = *(const float4*)(x + goff);
            o.x += xv.x; o.y += xv.y; o.z += xv.z; o.w += xv.w;
            *(float4*)(out + goff) = o;
        }
        __syncthreads();   // T reads done before next mt overwrites
    }
}

extern "C" void kernel_launch(void* const* d_in, const int* in_sizes, int n_in,
                              void* d_out, int out_size, void* d_ws, size_t ws_size,
                              hipStream_t stream)
{
    const float* x     = (const float*)d_in[0];
    const float* q_w   = (const float*)d_in[1];
    const float* q_b   = (const float*)d_in[2];
    const float* v_w   = (const float*)d_in[3];
    const float* v_b   = (const float*)d_in[4];
    const float* gamma = (const float*)d_in[5];
    float* out = (float*)d_out;

    unsigned short* qh = (unsigned short*)d_ws;            // 8*4096*32 bf16 = 2 MB
    unsigned short* ql = qh + (size_t)B_ * N_ * D_;        // 2 MB
    unsigned short* vT = ql + (size_t)B_ * N_ * D_;        // 8*256*4096 bf16 = 16 MB

    proj_kernel<<<B_ * (N_ / 64), 256, 0, stream>>>(x, q_w, q_b, v_w, v_b, qh, ql, vT);
    attn_kernel<<<B_ * (N_ / 64), 256, 0, stream>>>(qh, ql, vT, x, gamma, out);
}

// Round 3
// 259.830 us; speedup vs baseline: 6.9664x; 1.7387x over previous
//
#include <hip/hip_runtime.h>

#define B_   8
#define C_   256
#define D_   32
#define N_   4096
#define FMX  64.0f

typedef __attribute__((ext_vector_type(8))) short bf8_t;   // 8 bf16 (4 VGPRs)
typedef __attribute__((ext_vector_type(4))) float f4_t;    // MFMA C/D frag

__device__ __forceinline__ unsigned short f2bf(float f) {   // fp32 -> bf16 RNE
    unsigned int u = __builtin_bit_cast(unsigned int, f);
    u += 0x7FFFu + ((u >> 16) & 1u);
    return (unsigned short)(u >> 16);
}
__device__ __forceinline__ float bf2f(unsigned short h) {
    unsigned int u = ((unsigned int)h) << 16;
    return __builtin_bit_cast(float, u);
}

// ---------------------------------------------------------------------------
// Kernel 0: weight prep. v_w -> bf16 (row-major [oc][c], A-frag-ready);
// q_w -> bf16 hi/lo (for 3-term fp32-accurate q projection).
// ---------------------------------------------------------------------------
__global__ __launch_bounds__(256) void wprep_kernel(
    const float* __restrict__ qw, const float* __restrict__ vw,
    unsigned short* __restrict__ wqh, unsigned short* __restrict__ wql,
    unsigned short* __restrict__ wvb)
{
    const int gid = blockIdx.x * 256 + threadIdx.x;
    const int nthr = gridDim.x * 256;
    for (int idx = gid; idx < 16384; idx += nthr) {          // 256*256 / 4
        float4 v = ((const float4*)vw)[idx];
        uint2 u;
        u.x = f2bf(v.x) | ((unsigned)f2bf(v.y) << 16);
        u.y = f2bf(v.z) | ((unsigned)f2bf(v.w) << 16);
        ((uint2*)wvb)[idx] = u;
    }
    for (int idx = gid; idx < 2048; idx += nthr) {           // 32*256 / 4
        float4 v = ((const float4*)qw)[idx];
        unsigned short h0 = f2bf(v.x), h1 = f2bf(v.y), h2 = f2bf(v.z), h3 = f2bf(v.w);
        uint2 uh, ul;
        uh.x = h0 | ((unsigned)h1 << 16);  uh.y = h2 | ((unsigned)h3 << 16);
        ul.x = f2bf(v.x - bf2f(h0)) | ((unsigned)f2bf(v.y - bf2f(h1)) << 16);
        ul.y = f2bf(v.z - bf2f(h2)) | ((unsigned)f2bf(v.w - bf2f(h3)) << 16);
        ((uint2*)wqh)[idx] = uh;
        ((uint2*)wql)[idx] = ul;
    }
}

// ---------------------------------------------------------------------------
// Kernel 1: MFMA projections. Block = (b, 64-px tile), 256 threads.
// x staged in LDS as bf16 hi/lo in B-frag layout [c_hi(32)][i(64)][c_lo(8)].
// Wave w: V out-rows [w*64,(w+1)*64) x all 64 px; Q rows 0..31 x px [w*16,w*16+16).
// Q = wh.xh + wl.xh + wh.xl (3 MFMAs, ~fp32 accuracy). Outputs: qh/ql [b][i][d]
// hi/lo bf16, vT [b][c][i] bf16 (store-transposed through LDS).
// ---------------------------------------------------------------------------
__global__ __launch_bounds__(256, 2) void proj_kernel(
    const float* __restrict__ x, const unsigned short* __restrict__ wqh,
    const unsigned short* __restrict__ wql, const unsigned short* __restrict__ wvb,
    const float* __restrict__ qb, const float* __restrict__ vb,
    unsigned short* __restrict__ qh, unsigned short* __restrict__ ql,
    unsigned short* __restrict__ vT)
{
    __shared__ __align__(16) unsigned short S[32768];  // Xh @0, Xl @16384 (64 KiB)

    const int t    = threadIdx.x;
    const int lane = t & 63;
    const int w    = t >> 6;
    const int q4   = lane >> 4;
    const int l15  = lane & 15;
    const int b    = blockIdx.x >> 6;
    const int i0   = (blockIdx.x & 63) * 64;

    // ---- stage x tile -> bf16 hi/lo, frag layout [chi][i][clo] ----
    const float* xb = x + (size_t)b * C_ * N_;
    #pragma unroll
    for (int k = 0; k < 16; ++k) {
        int f4i = k * 256 + t;                 // 4096 float4s = 256c x 16
        int c = f4i >> 4, col = (f4i & 15) << 2;
        float4 v = *(const float4*)(xb + (size_t)c * N_ + i0 + col);
        int chi = c >> 3, clo = c & 7;
        float vv[4] = {v.x, v.y, v.z, v.w};
        #pragma unroll
        for (int j = 0; j < 4; ++j) {
            unsigned short h = f2bf(vv[j]);
            unsigned short l = f2bf(vv[j] - bf2f(h));
            S[chi * 512 + (col + j) * 8 + clo]         = h;
            S[16384 + chi * 512 + (col + j) * 8 + clo] = l;
        }
    }
    __syncthreads();

    f4_t acc[4][4];
    #pragma unroll
    for (int mt = 0; mt < 4; ++mt)
        #pragma unroll
        for (int nt = 0; nt < 4; ++nt) acc[mt][nt] = (f4_t)0.0f;
    f4_t qacc[2];
    qacc[0] = (f4_t)0.0f; qacc[1] = (f4_t)0.0f;

    // ---- k-loop: c = kk*32 + q4*8 + e ----
    #pragma unroll
    for (int kk = 0; kk < 8; ++kk) {
        bf8_t Bh[4];
        #pragma unroll
        for (int nt = 0; nt < 4; ++nt)
            Bh[nt] = *(const bf8_t*)&S[(kk * 4 + q4) * 512 + (nt * 16 + l15) * 8];
        bf8_t Bl = *(const bf8_t*)&S[16384 + (kk * 4 + q4) * 512 + (w * 16 + l15) * 8];

        bf8_t Av[4];
        #pragma unroll
        for (int mt = 0; mt < 4; ++mt)
            Av[mt] = *(const bf8_t*)&wvb[(w * 64 + mt * 16 + l15) * 256 + kk * 32 + q4 * 8];
        bf8_t Aqh[2], Aql[2];
        #pragma unroll
        for (int mq = 0; mq < 2; ++mq) {
            Aqh[mq] = *(const bf8_t*)&wqh[(mq * 16 + l15) * 256 + kk * 32 + q4 * 8];
            Aql[mq] = *(const bf8_t*)&wql[(mq * 16 + l15) * 256 + kk * 32 + q4 * 8];
        }

        #pragma unroll
        for (int mt = 0; mt < 4; ++mt)
            #pragma unroll
            for (int nt = 0; nt < 4; ++nt)
                acc[mt][nt] = __builtin_amdgcn_mfma_f32_16x16x32_bf16(
                    Av[mt], Bh[nt], acc[mt][nt], 0, 0, 0);
        #pragma unroll
        for (int mq = 0; mq < 2; ++mq) {
            qacc[mq] = __builtin_amdgcn_mfma_f32_16x16x32_bf16(Aqh[mq], Bh[w], qacc[mq], 0, 0, 0);
            qacc[mq] = __builtin_amdgcn_mfma_f32_16x16x32_bf16(Aql[mq], Bh[w], qacc[mq], 0, 0, 0);
            qacc[mq] = __builtin_amdgcn_mfma_f32_16x16x32_bf16(Aqh[mq], Bl,    qacc[mq], 0, 0, 0);
        }
    }

    // ---- Q epilogue: bias, hi/lo split, store qh/ql[b][i][32] ----
    {
        const int iq = i0 + w * 16 + l15;
        #pragma unroll
        for (int mq = 0; mq < 2; ++mq) {
            float4 qb4 = *(const float4*)(qb + mq * 16 + q4 * 4);
            float qv[4] = {qacc[mq][0] + qb4.x, qacc[mq][1] + qb4.y,
                           qacc[mq][2] + qb4.z, qacc[mq][3] + qb4.w};
            unsigned short hr[4], lr[4];
            #pragma unroll
            for (int r = 0; r < 4; ++r) {
                hr[r] = f2bf(qv[r]);
                lr[r] = f2bf(qv[r] - bf2f(hr[r]));
            }
            uint2 uh, ul;
            uh.x = hr[0] | ((unsigned)hr[1] << 16); uh.y = hr[2] | ((unsigned)hr[3] << 16);
            ul.x = lr[0] | ((unsigned)lr[1] << 16); ul.y = lr[2] | ((unsigned)lr[3] << 16);
            size_t qoff = ((size_t)b * N_ + iq) * D_ + mq * 16 + q4 * 4;
            *(uint2*)(qh + qoff) = uh;
            *(uint2*)(ql + qoff) = ul;
        }
    }

    // ---- V epilogue: bias, bf16, transpose through LDS, b128 stores ----
    __syncthreads();                 // all frag reads of S done
    #pragma unroll
    for (int mt = 0; mt < 4; ++mt) {
        float4 vb4 = *(const float4*)(vb + w * 64 + mt * 16 + q4 * 4);
        float bias[4] = {vb4.x, vb4.y, vb4.z, vb4.w};
        #pragma unroll
        for (int nt = 0; nt < 4; ++nt)
            #pragma unroll
            for (int r = 0; r < 4; ++r)
                S[(w * 64 + mt * 16 + q4 * 4 + r) * 64 + nt * 16 + l15] =
                    f2bf(acc[mt][nt][r] + bias[r]);
    }
    __syncthreads();
    #pragma unroll
    for (int k2 = 0; k2 < 8; ++k2) {
        int id = k2 * 256 + t;
        int oc = id >> 3, seg = id & 7;
        uint4 dat = *(const uint4*)&S[oc * 64 + seg * 8];
        *(uint4*)(vT + ((size_t)b * C_ + oc) * N_ + i0 + seg * 8) = dat;
    }
}

// ---------------------------------------------------------------------------
// Kernel 2: MFMA flash attention (unchanged from R2).
// ---------------------------------------------------------------------------
__global__ __launch_bounds__(256, 2) void attn_kernel(
    const unsigned short* __restrict__ qh, const unsigned short* __restrict__ ql,
    const unsigned short* __restrict__ vT, const float* __restrict__ x,
    const float* __restrict__ gamma_p, float* __restrict__ out)
{
    __shared__ __align__(16) unsigned short Vs[8 * 257 * 8];
    __shared__ __align__(16) unsigned short Pb[8 * 64 * 8];
    __shared__ __align__(16) float rowl[64];

    float* T = (float*)Vs;

    const int t    = threadIdx.x;
    const int lane = t & 63;
    const int w    = t >> 6;
    const int q4   = lane >> 4;
    const int l15  = lane & 15;
    const int b    = blockIdx.x >> 6;
    const int i0   = (blockIdx.x & 63) * 64;

    const unsigned short* qhb = qh + (size_t)b * N_ * D_;
    const unsigned short* qlb = ql + (size_t)b * N_ * D_;
    const unsigned short* vTb = vT + (size_t)b * C_ * N_;

    bf8_t Ah[4], Al[4];
    #pragma unroll
    for (int mt = 0; mt < 4; ++mt) {
        size_t off = (size_t)(i0 + mt * 16 + l15) * D_ + q4 * 8;
        Ah[mt] = *(const bf8_t*)(qhb + off);
        Al[mt] = *(const bf8_t*)(qlb + off);
    }

    f4_t acc[4][4];
    #pragma unroll
    for (int mt = 0; mt < 4; ++mt)
        #pragma unroll
        for (int nt = 0; nt < 4; ++nt) acc[mt][nt] = (f4_t)0.0f;

    f4_t lacc[4];
    #pragma unroll
    for (int mt = 0; mt < 4; ++mt) lacc[mt] = (f4_t)0.0f;
    bf8_t onesb;
    #pragma unroll
    for (int e = 0; e < 8; ++e) onesb[e] = (short)0x3F80;

    for (int jt = 0; jt < N_ / 64; ++jt) {
        const int j0 = jt * 64;

        size_t koff = (size_t)(j0 + w * 16 + l15) * D_ + q4 * 8;
        bf8_t Bh = *(const bf8_t*)(qhb + koff);
        bf8_t Bl = *(const bf8_t*)(qlb + koff);

        __syncthreads();

        #pragma unroll
        for (int r = 0; r < 8; ++r) {
            int idx = r * 256 + t;
            int c = idx >> 3, part = idx & 7;
            uint4 d = *(const uint4*)(vTb + (size_t)c * N_ + j0 + part * 8);
            *(uint4*)(&Vs[(part * 257 + c) * 8]) = d;
        }

        f4_t s[4];
        #pragma unroll
        for (int mt = 0; mt < 4; ++mt) {
            f4_t a = (f4_t)0.0f;
            a = __builtin_amdgcn_mfma_f32_16x16x32_bf16(Ah[mt], Bh, a, 0, 0, 0);
            a = __builtin_amdgcn_mfma_f32_16x16x32_bf16(Ah[mt], Bl, a, 0, 0, 0);
            a = __builtin_amdgcn_mfma_f32_16x16x32_bf16(Al[mt], Bh, a, 0, 0, 0);
            s[mt] = a;
        }

        const int jl = w * 16 + l15;
        const int pprt = jl >> 3, jlo = jl & 7;
        #pragma unroll
        for (int mt = 0; mt < 4; ++mt)
            #pragma unroll
            for (int r = 0; r < 4; ++r) {
                float p = __expf(s[mt][r] - FMX);
                Pb[(pprt * 64 + mt * 16 + q4 * 4 + r) * 8 + jlo] = f2bf(p);
            }

        __syncthreads();

        #pragma unroll
        for (int kk = 0; kk < 2; ++kk) {
            bf8_t Af[4], Bf[4];
            #pragma unroll
            for (int mt = 0; mt < 4; ++mt)
                Af[mt] = *(const bf8_t*)(&Pb[((kk * 4 + q4) * 64 + mt * 16 + l15) * 8]);
            #pragma unroll
            for (int nt = 0; nt < 4; ++nt)
                Bf[nt] = *(const bf8_t*)(&Vs[((kk * 4 + q4) * 257 + w * 64 + nt * 16 + l15) * 8]);
            #pragma unroll
            for (int mt = 0; mt < 4; ++mt)
                #pragma unroll
                for (int nt = 0; nt < 4; ++nt)
                    acc[mt][nt] = __builtin_amdgcn_mfma_f32_16x16x32_bf16(
                        Af[mt], Bf[nt], acc[mt][nt], 0, 0, 0);
            if (w == 3) {
                #pragma unroll
                for (int mt = 0; mt < 4; ++mt)
                    lacc[mt] = __builtin_amdgcn_mfma_f32_16x16x32_bf16(
                        Af[mt], onesb, lacc[mt], 0, 0, 0);
            }
        }
    }

    __syncthreads();
    if (w == 3 && l15 == 0) {
        #pragma unroll
        for (int mt = 0; mt < 4; ++mt)
            #pragma unroll
            for (int r = 0; r < 4; ++r)
                rowl[mt * 16 + q4 * 4 + r] = lacc[mt][r];
    }
    __syncthreads();

    const float g = gamma_p[0];
    for (int mt = 0; mt < 4; ++mt) {
        float4 rl = *(float4*)(&rowl[mt * 16 + q4 * 4]);
        float inv[4] = { g / rl.x, g / rl.y, g / rl.z, g / rl.w };
        #pragma unroll
        for (int nt = 0; nt < 4; ++nt)
            #pragma unroll
            for (int r = 0; r < 4; ++r)
                T[(w * 64 + nt * 16 + l15) * 17 + q4 * 4 + r] = acc[mt][nt][r] * inv[r];
        __syncthreads();
        #pragma unroll
        for (int pass = 0; pass < 4; ++pass) {
            int c  = pass * 64 + (t >> 2);
            int ii = (t & 3) * 4;
            float4 o;
            o.x = T[c * 17 + ii];     o.y = T[c * 17 + ii + 1];
            o.z = T[c * 17 + ii + 2]; o.w = T[c * 17 + ii + 3];
            size_t goff = ((size_t)b * C_ + c) * N_ + i0 + mt * 16 + ii;
            float4 xv = *(const float4*)(x + goff);
            o.x += xv.x; o.y += xv.y; o.z += xv.z; o.w += xv.w;
            *(float4*)(out + goff) = o;
        }
        __syncthreads();
    }
}

extern "C" void kernel_launch(void* const* d_in, const int* in_sizes, int n_in,
                              void* d_out, int out_size, void* d_ws, size_t ws_size,
                              hipStream_t stream)
{
    const float* x     = (const float*)d_in[0];
    const float* q_w   = (const float*)d_in[1];
    const float* q_b   = (const float*)d_in[2];
    const float* v_w   = (const float*)d_in[3];
    const float* v_b   = (const float*)d_in[4];
    const float* gamma = (const float*)d_in[5];
    float* out = (float*)d_out;

    unsigned short* ws16 = (unsigned short*)d_ws;
    unsigned short* qhp = ws16;                          // 8*4096*32  = 1M u16
    unsigned short* qlp = ws16 + 1048576;                // 1M u16
    unsigned short* vTp = ws16 + 2097152;                // 8*256*4096 = 8M u16
    unsigned short* wvb = ws16 + 10485760;               // 64K u16
    unsigned short* wqh = wvb + 65536;                   // 8K u16
    unsigned short* wql = wqh + 8192;                    // 8K u16

    wprep_kernel<<<24, 256, 0, stream>>>(q_w, v_w, wqh, wql, wvb);
    proj_kernel<<<B_ * (N_ / 64), 256, 0, stream>>>(x, wqh, wql, wvb, q_b, v_b,
                                                    qhp, qlp, vTp);
    attn_kernel<<<B_ * (N_ / 64), 256, 0, stream>>>(qhp, qlp, vTp, x, gamma, out);
}